// Round 8
// baseline (503.753 us; speedup 1.0000x reference)
//
#include <hip/hip_runtime.h>
#include <cstddef>
#include <cstdint>

// ---------------------------------------------------------------------------
// Swin block. f32 in/out; internal bf16 MFMA. B=8 H=W=64 DIM=512 NH=16 HD=32.
// GEMM: gemm256 = 256x128 tile, BK=64, 512 threads (8 waves 4Mx2N, 64x64 per
// wave), 3-slot LDS ring (3x48KB=144KB), global_load_lds width=16, counted
// vmcnt(6)+lgkmcnt(0) boundaries (loads 2 tiles deep; never drained to 0 in
// the steady loop), raw s_barrier, setprio around MFMA clusters.
// *** R5-R7 POST-MORTEM: all three "sync" failures were ONE grid typo —
// QKV launched dim3(12,64) = M 16384, but the block has 32768 tokens
// (B*H*W = 8*64*64). Half of q/k/v was stale => deterministic absmax
// 0.2421875 across three different sync schemes. Fixed: dim3(12,128).
// When an error is bit-identical across schedule variants, audit grid and
// indexing before suspecting races. ***
// Ring safety (re-audited): loop-body VMEM ops are EXACTLY the 6
// global_load_lds per stage (bias/auxf/C-writes are post-loop), so vmcnt
// counts are sound; (512,1) leaves 256-VGPR headroom (no spill traffic to
// corrupt the count; est. use ~130). Steady boundary: outstanding <= 12,
// vmcnt(6) retires stage(t+1) fully (FIFO-older); lgkmcnt(0) retires this
// wave's ds_reads of slot t%3 before stage(t+3) may overwrite it; slot
// (t+2)%3 was last read epoch t-1, drained at that boundary.
// Bank-conflict scheme (verified R1-R4, conflicts=0): LDS dest linear,
// global SOURCE chunk XOR-swizzled (c ^= row&7), same XOR on ds_read side.
// T1: bijective XCD swizzle (verified R4: QKV FETCH 135->28MB).
// M_GELU uses branch-free A&S 7.1.26 erf (verified R3).
// launch_bounds: do NOT trade VGPRs for phantom occupancy (R2: 803us).
// ws: [0,6.3M) bf16 weights | q[8,40) k[40,72) v[72,104) MB
//     h2 overlays q after proj; gbuf (2x 16384x2048 bf16) overlays k+v.
// xw (LN1+shift, bf16 32MB) lives in d_out (dead until proj overwrites it).
// ---------------------------------------------------------------------------

typedef unsigned short u16;
typedef __attribute__((ext_vector_type(8))) short short8;
typedef __attribute__((ext_vector_type(4))) float floatx4;

__device__ __forceinline__ float bf2f(u16 u) {
    union { float f; unsigned i; } w; w.i = ((unsigned)u) << 16; return w.f;
}
__device__ __forceinline__ u16 f2bf(float f) {
    union { float f; unsigned i; } w; w.f = f;
    unsigned r = w.i + 0x7FFF + ((w.i >> 16) & 1);   // RNE
    return (u16)(r >> 16);
}

__device__ __forceinline__ void gload_lds16(const u16* g, u16* l) {
    __builtin_amdgcn_global_load_lds(
        (const __attribute__((address_space(1))) void*)g,
        (__attribute__((address_space(3))) void*)l, 16, 0, 0);
}

// Epoch boundary: wait newest-6 VMEM (tile t+1 landed in LDS, tile t+2 still
// in flight) AND all this-wave LDS reads done, then barrier. sched_barrier
// fences so nothing (incl. reg-only MFMA) migrates across the boundary.
__device__ __forceinline__ void ring_bar6() {
    __builtin_amdgcn_sched_barrier(0);
    asm volatile("s_waitcnt vmcnt(6) lgkmcnt(0)\n\ts_barrier" ::: "memory");
    __builtin_amdgcn_sched_barrier(0);
}
__device__ __forceinline__ void ring_bar0() {
    __builtin_amdgcn_sched_barrier(0);
    asm volatile("s_waitcnt vmcnt(0) lgkmcnt(0)\n\ts_barrier" ::: "memory");
    __builtin_amdgcn_sched_barrier(0);
}

// branch-free erf, A&S 7.1.26, |err| < 1.5e-7 (invisible at bf16 precision)
__device__ __forceinline__ float erf_fast(float x) {
    float ax = fabsf(x);
    float t = 1.0f / (1.0f + 0.3275911f * ax);
    float poly = ((((1.061405429f * t - 1.453152027f) * t + 1.421413741f) * t
                   - 0.284496736f) * t + 0.254829592f) * t;
    float er = 1.0f - poly * __expf(-ax * ax);
    return copysignf(er, x);
}

__device__ __forceinline__ int win_to_img_row(int t) {
    int win = t >> 6, n = t & 63;
    int b = win >> 6, wr = (win >> 3) & 7, wc = win & 7;
    int h = ((wr << 3) + (n >> 3) + 4) & 63;
    int w = ((wc << 3) + (n & 7) + 4) & 63;
    return (b << 12) + (h << 6) + w;
}

// ---------------------------------------------------------------------------
// Fused LayerNorm: one wave per 512-dim row, single pass.
// ---------------------------------------------------------------------------
__global__ __launch_bounds__(256) void ln_fused(
    const float* __restrict__ x, const float* __restrict__ g,
    const float* __restrict__ b, u16* __restrict__ out, int gather)
{
    int wave = threadIdx.x >> 6, lane = threadIdx.x & 63;
    int t = blockIdx.x * 4 + wave;
    int src = gather ? win_to_img_row(t) : t;
    const float* xr = x + (size_t)src * 512 + lane * 8;
    float4 a = *(const float4*)xr;
    float4 c = *(const float4*)(xr + 4);
    float s = a.x + a.y + a.z + a.w + c.x + c.y + c.z + c.w;
    float s2 = a.x*a.x + a.y*a.y + a.z*a.z + a.w*a.w
             + c.x*c.x + c.y*c.y + c.z*c.z + c.w*c.w;
#pragma unroll
    for (int off = 32; off; off >>= 1) { s += __shfl_down(s, off); s2 += __shfl_down(s2, off); }
    s = __shfl(s, 0); s2 = __shfl(s2, 0);
    float mu = s * (1.f / 512.f);
    float var = s2 * (1.f / 512.f) - mu * mu;
    float rs = rsqrtf(var + 1e-5f);
    int col = lane * 8;
    float4 g0 = *(const float4*)(g + col), g1 = *(const float4*)(g + col + 4);
    float4 b0 = *(const float4*)(b + col), b1 = *(const float4*)(b + col + 4);
    u16 r[8];
    r[0] = f2bf((a.x - mu) * rs * g0.x + b0.x);
    r[1] = f2bf((a.y - mu) * rs * g0.y + b0.y);
    r[2] = f2bf((a.z - mu) * rs * g0.z + b0.z);
    r[3] = f2bf((a.w - mu) * rs * g0.w + b0.w);
    r[4] = f2bf((c.x - mu) * rs * g1.x + b1.x);
    r[5] = f2bf((c.y - mu) * rs * g1.y + b1.y);
    r[6] = f2bf((c.z - mu) * rs * g1.z + b1.z);
    r[7] = f2bf((c.w - mu) * rs * g1.w + b1.w);
    *(uint4*)(out + (size_t)t * 512 + col) = *(const uint4*)r;
}

__global__ __launch_bounds__(256) void transpose_k(
    const float* __restrict__ W, u16* __restrict__ WT, int K, int N)
{
    int f = blockIdx.x * 256 + threadIdx.x;
    int n = f % N, kc = f / N;
    if (kc >= (K >> 3)) return;
    int k0 = kc << 3;
    u16 r[8];
#pragma unroll
    for (int j = 0; j < 8; ++j) r[j] = f2bf(W[(size_t)(k0 + j) * N + n]);
    *(uint4*)(WT + (size_t)n * K + k0) = *(const uint4*)r;
}

// ---------------------------------------------------------------------------
// gemm256: 256x128 tile, BK=64, 3-slot ring pipeline. See header comment.
// Slot layout (u16): A[256][64] at +0 (16384), B[128][64] at +16384 (8192).
// LDS[row][c] holds global chunk (c ^ (row&7)) of the row -> ds_read applies
// the same XOR. Staging: A 4 loads/thread, B 2 -> 6/thread/tile = vmcnt unit.
// ASRC: 0 plain bf16 A[lda] | 3 bf16 qkv-slice gather.
// ---------------------------------------------------------------------------
enum { M_QKV = 0, M_PROJ = 1, M_GELU = 2, M_FINAL = 3 };

template <int MODE, int ASRC>
__global__ __launch_bounds__(512, 1) void gemm256(
    const u16* __restrict__ A, int lda,
    const u16* __restrict__ BT, int ldb,
    const float* __restrict__ bias,
    void* __restrict__ outp, const float* __restrict__ auxf, int K)
{
    __shared__ __align__(16) u16 lds[3 * 24576];   // 144 KiB

    int tid = threadIdx.x;
    // ---- T1: bijective XCD-aware block swizzle (8 XCDs) ----
    int nwg = gridDim.x * gridDim.y;
    int bid = blockIdx.y * gridDim.x + blockIdx.x;
    int q8 = nwg >> 3, r8 = nwg & 7;
    int xcd = bid & 7, pos = bid >> 3;
    int swz = (xcd < r8 ? xcd * (q8 + 1)
                        : r8 * (q8 + 1) + (xcd - r8) * q8) + pos;
    int bx = swz % gridDim.x, by = swz / gridDim.x;
    int bm = by * 256, bn = bx * 128;

    int wave = tid >> 6, lane = tid & 63;
    int quad = lane >> 4, lr = lane & 15;
    int wm = (wave >> 1) * 64, wn = (wave & 1) * 64;   // 4M x 2N waves

    floatx4 acc[4][4] = {};
    int nt = K >> 6;

    auto stage = [&](int t) {
        u16* slot = lds + (t % 3) * 24576;
        int k0 = t << 6;
#pragma unroll
        for (int l = 0; l < 4; ++l) {                  // A: 2048 chunks
            int f = (l << 9) + tid;
            int row = f >> 3, c = f & 7;
            int kk = k0 + ((c ^ (row & 7)) << 3);      // source-side XOR
            if constexpr (ASRC == 0) {
                gload_lds16(A + (size_t)(bm + row) * lda + kk, slot + f * 8);
            } else {  // qkv-slice gather: [ (win*16+head)*2048 + tok*32 + d ]
                int m = bm + row;
                gload_lds16(A + (size_t)(((m >> 6) << 4) + (kk >> 5)) * 2048
                              + (m & 63) * 32 + (kk & 31), slot + f * 8);
            }
        }
#pragma unroll
        for (int l = 0; l < 2; ++l) {                  // B: 1024 chunks
            int f = (l << 9) + tid;
            int row = f >> 3, c = f & 7;
            int kk = k0 + ((c ^ (row & 7)) << 3);
            gload_lds16(BT + (size_t)(bn + row) * ldb + kk,
                        slot + 16384 + f * 8);
        }
    };

    auto compute = [&](int t) {
        const u16* As = lds + (t % 3) * 24576;
        const u16* Bs = As + 16384;
#pragma unroll
        for (int step = 0; step < 2; ++step) {
            short8 af[4], bv[4];
            int kc = step * 4 + quad;
#pragma unroll
            for (int tt = 0; tt < 4; ++tt) {
                int ra = wm + tt * 16 + lr;
                int rb = wn + tt * 16 + lr;
                af[tt] = *(const short8*)(As + ra * 64 + ((kc ^ (ra & 7)) << 3));
                bv[tt] = *(const short8*)(Bs + rb * 64 + ((kc ^ (rb & 7)) << 3));
            }
            __builtin_amdgcn_s_setprio(1);
#pragma unroll
            for (int mt = 0; mt < 4; ++mt)
#pragma unroll
                for (int nn = 0; nn < 4; ++nn)
                    acc[mt][nn] = __builtin_amdgcn_mfma_f32_16x16x32_bf16(
                        af[mt], bv[nn], acc[mt][nn], 0, 0, 0);
            __builtin_amdgcn_s_setprio(0);
        }
    };

    // prologue: 2 tiles in flight, wait for tile 0 (12 issued, keep newest 6)
    stage(0);
    stage(1);
    ring_bar6();
    // steady state: stage t+2 (slot dead since epoch t-1, reads drained at
    // that boundary's lgkmcnt(0)), compute t, boundary waits tile t+1 landed.
    for (int t = 0; t + 2 < nt; ++t) {
        stage(t + 2);
        compute(t);
        ring_bar6();
    }
    compute(nt - 2);
    ring_bar0();              // drain: tile nt-1 fully landed
    compute(nt - 1);

#pragma unroll
    for (int mt = 0; mt < 4; ++mt) {
#pragma unroll
        for (int nn = 0; nn < 4; ++nn) {
            int m0 = bm + wm + mt * 16 + quad * 4;
            int n = bn + wn + nn * 16 + lr;
#pragma unroll
            for (int i = 0; i < 4; ++i) {
                int m = m0 + i;
                float v = acc[mt][nn][i];
                if constexpr (MODE == M_QKV) {
                    v += bias[n];
                    int sel = n >> 9, head = (n >> 5) & 15, d = n & 31;
                    int wh = (m >> 6) * 16 + head, tok = m & 63;
                    ((u16*)outp)[(size_t)sel * 16777216 + (size_t)wh * 2048 + tok * 32 + d] = f2bf(v);
                } else if constexpr (MODE == M_PROJ) {
                    size_t idx = (size_t)win_to_img_row(m) * 512 + n;
                    ((float*)outp)[idx] = v + bias[n] + auxf[idx];
                } else if constexpr (MODE == M_GELU) {
                    v += bias[n];
                    float gel = 0.5f * v * (1.0f + erf_fast(v * 0.70710678118654752f));
                    ((u16*)outp)[(size_t)m * 2048 + n] = f2bf(gel);
                } else { // M_FINAL: outp = xres f32, read-modify-write
                    size_t idx = (size_t)m * 512 + n;
                    float* o = (float*)outp;
                    o[idx] = o[idx] + v + bias[n];
                }
            }
        }
    }
}

// ---------------------------------------------------------------------------
// MFMA attention (unchanged): block = 4 waves = 4 windows x 1 head.
// No T1 here: each block reads private q/k/v rows (zero inter-block reuse).
// ---------------------------------------------------------------------------
__global__ __launch_bounds__(256) void attn_mfma(
    const u16* __restrict__ qkv, const float* __restrict__ table,
    u16* __restrict__ outp)
{
    __shared__ __align__(8) u16 PT[4][64 * 76];
    __shared__ float blds[225];

    int w = threadIdx.x >> 6, lane = threadIdx.x & 63;
    int head = blockIdx.x & 15, win = ((blockIdx.x >> 4) << 2) + w;
    int wh = (win << 4) + head;
    int quad = lane >> 4, lr = lane & 15;
    const u16* qb = qkv + (size_t)wh * 2048;
    const u16* kb = qb + 16777216;
    const u16* vb = qb + 33554432;
    u16* PTw = PT[w];

    for (int i = threadIdx.x; i < 225; i += 256) blds[i] = table[i * 16 + head];
    __syncthreads();

    short8 qf[4], kf[4];
#pragma unroll
    for (int t = 0; t < 4; ++t) {
        qf[t] = *(const short8*)(qb + (t * 16 + lr) * 32 + quad * 8);
        kf[t] = *(const short8*)(kb + (t * 16 + lr) * 32 + quad * 8);
    }
    floatx4 s[4][4] = {};
#pragma unroll
    for (int mi = 0; mi < 4; ++mi)
#pragma unroll
        for (int ni = 0; ni < 4; ++ni)
            s[mi][ni] = __builtin_amdgcn_mfma_f32_16x16x32_bf16(qf[mi], kf[ni], s[mi][ni], 0, 0, 0);

    short8 vf[2][2];
#pragma unroll
    for (int ks = 0; ks < 2; ++ks)
#pragma unroll
        for (int nd = 0; nd < 2; ++nd)
#pragma unroll
            for (int j = 0; j < 8; ++j)
                vf[ks][nd][j] = (short)vb[(ks * 32 + quad * 8 + j) * 32 + nd * 16 + lr];

    int wr = (win >> 3) & 7, wc = win & 7;
    int rj[4], cj[4], regj[4];
#pragma unroll
    for (int ni = 0; ni < 4; ++ni) {
        int kj = ni * 16 + lr;
        rj[ni] = kj >> 3; cj[ni] = kj & 7;
        int hJ = wr * 8 + rj[ni], wJ = wc * 8 + cj[ni];
        regj[ni] = (hJ < 56 ? 0 : (hJ < 60 ? 1 : 2)) * 3 + (wJ < 56 ? 0 : (wJ < 60 ? 1 : 2));
    }
    float rm[4][4], linv[4][4];
#pragma unroll
    for (int mi = 0; mi < 4; ++mi) {
#pragma unroll
        for (int i = 0; i < 4; ++i) {
            int qi = mi * 16 + quad * 4 + i;
            int ri = qi >> 3, ci = qi & 7;
            int hI = wr * 8 + ri, wI = wc * 8 + ci;
            int regi = (hI < 56 ? 0 : (hI < 60 ? 1 : 2)) * 3 + (wI < 56 ? 0 : (wI < 60 ? 1 : 2));
            float mx = -1e30f;
#pragma unroll
            for (int ni = 0; ni < 4; ++ni) {
                float v = s[mi][ni][i] * 0.17677669529663687f
                        + blds[(ri - rj[ni] + 7) * 15 + (ci - cj[ni] + 7)];
                if (regj[ni] != regi) v -= 100.f;
                s[mi][ni][i] = v;
                mx = fmaxf(mx, v);
            }
            rm[mi][i] = mx;
        }
    }
#pragma unroll
    for (int mi = 0; mi < 4; ++mi)
#pragma unroll
        for (int i = 0; i < 4; ++i) {
            float mx = rm[mi][i];
#pragma unroll
            for (int msk = 1; msk < 16; msk <<= 1) mx = fmaxf(mx, __shfl_xor(mx, msk));
            float sum = 0.f;
#pragma unroll
            for (int ni = 0; ni < 4; ++ni) {
                float e = __expf(s[mi][ni][i] - mx);
                s[mi][ni][i] = e;
                sum += e;
            }
#pragma unroll
            for (int msk = 1; msk < 16; msk <<= 1) sum += __shfl_xor(sum, msk);
            linv[mi][i] = 1.f / sum;
        }

#pragma unroll
    for (int mi = 0; mi < 4; ++mi)
#pragma unroll
        for (int ni = 0; ni < 4; ++ni) {
            unsigned lo = (unsigned)f2bf(s[mi][ni][0]) | ((unsigned)f2bf(s[mi][ni][1]) << 16);
            unsigned hi = (unsigned)f2bf(s[mi][ni][2]) | ((unsigned)f2bf(s[mi][ni][3]) << 16);
            uint2 pk = make_uint2(lo, hi);
            *(uint2*)(PTw + (ni * 16 + lr) * 76 + mi * 16 + quad * 4) = pk;
        }
    __syncthreads();

    floatx4 o[4][2] = {};
#pragma unroll
    for (int mi = 0; mi < 4; ++mi) {
#pragma unroll
        for (int ks = 0; ks < 2; ++ks) {
            short8 pa;
#pragma unroll
            for (int j = 0; j < 8; ++j)
                pa[j] = (short)PTw[(ks * 32 + quad * 8 + j) * 76 + mi * 16 + lr];
#pragma unroll
            for (int nd = 0; nd < 2; ++nd)
                o[mi][nd] = __builtin_amdgcn_mfma_f32_16x16x32_bf16(pa, vf[ks][nd], o[mi][nd], 0, 0, 0);
        }
    }
    u16* ob = outp + (size_t)wh * 2048;
#pragma unroll
    for (int mi = 0; mi < 4; ++mi)
#pragma unroll
        for (int nd = 0; nd < 2; ++nd)
#pragma unroll
            for (int i = 0; i < 4; ++i) {
                int qi = mi * 16 + quad * 4 + i;
                ob[qi * 32 + nd * 16 + lr] = f2bf(o[mi][nd][i] * linv[mi][i]);
            }
}

// ---------------------------------------------------------------------------
extern "C" void kernel_launch(void* const* d_in, const int* in_sizes, int n_in,
                              void* d_out, int out_size, void* d_ws, size_t ws_size,
                              hipStream_t stream)
{
    (void)in_sizes; (void)n_in; (void)out_size; (void)ws_size;
    const float* x      = (const float*)d_in[0];
    const float* n1g    = (const float*)d_in[2];
    const float* n1b    = (const float*)d_in[3];
    const float* qkv_w  = (const float*)d_in[4];
    const float* qkv_b  = (const float*)d_in[5];
    const float* table  = (const float*)d_in[6];
    const float* proj_w = (const float*)d_in[7];
    const float* proj_b = (const float*)d_in[8];
    const float* n2g    = (const float*)d_in[9];
    const float* n2b    = (const float*)d_in[10];
    const float* fc1_w  = (const float*)d_in[11];
    const float* fc1_b  = (const float*)d_in[12];
    const float* fc2_w  = (const float*)d_in[13];
    const float* fc2_b  = (const float*)d_in[14];
    float* out = (float*)d_out;
    char* ws = (char*)d_ws;

    u16* qkvT  = (u16*)ws;                  // 786432
    u16* projT = qkvT + 786432;             // 262144
    u16* fc1T  = projT + 262144;            // 1048576
    u16* fc2T  = fc1T + 1048576;            // 1048576 (ends 6,291,456 B)
    u16* q    = (u16*)(ws + 8388608);       // q,k,v 3x32MB (ends 104 MB)
    u16* h2   = q;                          // overlays q after proj
    u16* gbuf = q + 16777216;               // 64 MB over k+v (dead post-attn)
    u16* xw   = (u16*)d_out;                // LN1+shift bf16, dead before proj

    transpose_k<<<384, 256, 0, stream>>>(qkv_w, qkvT, 512, 1536);
    transpose_k<<<128, 256, 0, stream>>>(proj_w, projT, 512, 512);
    transpose_k<<<512, 256, 0, stream>>>(fc1_w, fc1T, 512, 2048);
    transpose_k<<<512, 256, 0, stream>>>(fc2_w, fc2T, 2048, 512);

    // LN1 + shift/window gather -> xw (in d_out)
    ln_fused<<<8192, 256, 0, stream>>>(x, n1g, n1b, xw, 1);
    // QKV from xw (M=32768 = 128 blocks x 256 rows — R5-R7 bug was 64 here)
    gemm256<M_QKV, 0><<<dim3(12, 128), 512, 0, stream>>>(
        xw, 512, qkvT, 512, qkv_b, q, nullptr, 512);
    attn_mfma<<<2048, 256, 0, stream>>>(q, table, q);
    // proj + reverse-shift scatter + residual -> d_out (M=32768, N=512, K=512)
    gemm256<M_PROJ, 3><<<dim3(4, 128), 512, 0, stream>>>(
        q, 0, projT, 512, proj_b, out, x, 512);
    // LN2 -> h2
    ln_fused<<<8192, 256, 0, stream>>>(out, n2g, n2b, h2, 0);
    for (int mc = 0; mc < 2; ++mc) {
        // fc1+gelu (M=16384 = 64 x 256, N=2048, K=512)
        gemm256<M_GELU, 0><<<dim3(16, 64), 512, 0, stream>>>(
            h2 + (size_t)mc * 16384 * 512, 512, fc1T, 512, fc1_b,
            gbuf, nullptr, 512);
        // fc2+residual (M=16384, N=512, K=2048)
        gemm256<M_FINAL, 0><<<dim3(4, 64), 512, 0, stream>>>(
            gbuf, 2048, fc2T, 2048, fc2_b,
            out + (size_t)mc * 16384 * 512, nullptr, 2048);
    }
}